// Round 2
// baseline (82.272 us; speedup 1.0000x reference)
//
#include <hip/hip_runtime.h>
#include <stdint.h>

#define FP8_MAX 448.0f

typedef __attribute__((ext_vector_type(4))) float f32x4;
typedef long long ll;

// flax fp8_ops.compute_scale: sf = fp8_max/amax with fallbacks; qdq multiplier.
__device__ __forceinline__ float scale_factor(float amax, float prev_scale) {
    float sf = FP8_MAX / amax;
    if (!(amax > 0.0f) || !isfinite(amax)) sf = 1.0f / prev_scale;
    return sf;
}

__device__ __forceinline__ unsigned pack4_fp8(float a, float b, float c, float d) {
    int v = __builtin_amdgcn_cvt_pk_fp8_f32(a, b, 0, false);
    v = __builtin_amdgcn_cvt_pk_fp8_f32(c, d, v, true);
    return (unsigned)v;
}

__device__ __forceinline__ float qclamp(float x, float sf) {
    return fminf(fmaxf(x * sf, -FP8_MAX), FP8_MAX);
}

// ---------------------------------------------------------------------------
// fused amax over x (blocks [0,XBLK)) and k (blocks [XBLK,grid)), float4 loads,
// wave shuffle-reduce, one atomicMax(float-bits) per block.
// ---------------------------------------------------------------------------
#define XBLK 2048
__global__ void amax2_kernel(const float* __restrict__ x, unsigned n4x,
                             const float* __restrict__ k, unsigned n4k,
                             unsigned* __restrict__ out) {
    bool isx = blockIdx.x < XBLK;
    const f32x4* p = (const f32x4*)(isx ? x : k);
    unsigned n4 = isx ? n4x : n4k;
    unsigned bid = isx ? blockIdx.x : blockIdx.x - XBLK;
    unsigned nb = isx ? XBLK : (gridDim.x - XBLK);
    unsigned stride = nb * blockDim.x;

    float m = 0.0f;
    for (unsigned i = bid * blockDim.x + threadIdx.x; i < n4; i += stride) {
        f32x4 v = p[i];
        float a0 = fmaxf(__builtin_fabsf(v.x), __builtin_fabsf(v.y));
        float a1 = fmaxf(__builtin_fabsf(v.z), __builtin_fabsf(v.w));
        m = fmaxf(m, fmaxf(a0, a1));
    }
    #pragma unroll
    for (int off = 32; off; off >>= 1)
        m = fmaxf(m, __shfl_down(m, off, 64));
    __shared__ float sm[4];
    int lane = threadIdx.x & 63;
    int w = threadIdx.x >> 6;
    if (lane == 0) sm[w] = m;
    __syncthreads();
    if (threadIdx.x == 0) {
        float mm = fmaxf(fmaxf(sm[0], sm[1]), fmaxf(sm[2], sm[3]));
        atomicMax(out + (isx ? 0 : 1), __float_as_uint(mm));
    }
}

// ---------------------------------------------------------------------------
// quantize k [256(d),256(f)] into MFMA B-fragment layout:
//   pack[kstep*1024 + ntile*64 + lane], byte j: col=ntile*16+(lane&15),
//   k = kstep*32 + (lane>>4)*8 + j
// ---------------------------------------------------------------------------
__global__ void pack_k_kernel(const float* __restrict__ kin,
                              const unsigned* __restrict__ amax_bits,
                              const float* __restrict__ prev_scale,
                              ll* __restrict__ pack) {
    float amax = __uint_as_float(amax_bits[1]);
    float sf = scale_factor(amax, prev_scale[0]);
    int t = blockIdx.x * blockDim.x + threadIdx.x;  // 0..8191
    if (t >= 8192) return;
    int lane = t & 63;
    int nt = (t >> 6) & 15;
    int kstep = t >> 10;
    int col = nt * 16 + (lane & 15);
    int k0 = kstep * 32 + (lane >> 4) * 8;
    float v[8];
    #pragma unroll
    for (int j = 0; j < 8; ++j)
        v[j] = qclamp(kin[(k0 + j) * 256 + col], sf);
    unsigned lo = pack4_fp8(v[0], v[1], v[2], v[3]);
    unsigned hi = pack4_fp8(v[4], v[5], v[6], v[7]);
    pack[t] = (ll)lo | ((ll)hi << 32);
}

// ---------------------------------------------------------------------------
// GEMM: C[M,256] = qdq(x)[M,256] * qdq(k)[256,256] via fp8 MFMA.
// 4 waves/block; wave w owns N cols [w*64, w*64+64) -> its full B slice
// (8 ks x 4 nt fragments = 64 VGPRs) is PRELOADED into registers once.
// Grid-strides over 16-row M-tiles; inner loop = A load + quant + 32 MFMA.
// ---------------------------------------------------------------------------
__global__ __launch_bounds__(256) void gemm_kernel(
    const float* __restrict__ x, const ll* __restrict__ Bpack,
    const unsigned* __restrict__ amax_bits,
    const float* __restrict__ ps_x, const float* __restrict__ ps_k,
    float* __restrict__ C, int ntiles) {
    float sf_x = scale_factor(__uint_as_float(amax_bits[0]), ps_x[0]);
    float sf_k = scale_factor(__uint_as_float(amax_bits[1]), ps_k[0]);
    float outscale = (1.0f / sf_x) * (1.0f / sf_k);

    int w = threadIdx.x >> 6;                 // wave id: N-quarter
    int lane = threadIdx.x & 63;
    int kg = lane >> 4;                       // 0..3
    int r16 = lane & 15;

    // Preload this wave's entire B slice into registers.
    ll Breg[8][4];
    #pragma unroll
    for (int ks = 0; ks < 8; ++ks)
        #pragma unroll
        for (int j = 0; j < 4; ++j)
            Breg[ks][j] = Bpack[ks * 1024 + (w * 4 + j) * 64 + lane];

    for (int tile = blockIdx.x; tile < ntiles; tile += gridDim.x) {
        const float* xp = x + (size_t)(tile * 16 + r16) * 256 + kg * 8;
        f32x4 acc[4];
        #pragma unroll
        for (int j = 0; j < 4; ++j) acc[j] = (f32x4){0.f, 0.f, 0.f, 0.f};

        #pragma unroll
        for (int ks = 0; ks < 8; ++ks) {
            f32x4 a0 = *(const f32x4*)(xp + ks * 32);
            f32x4 a1 = *(const f32x4*)(xp + ks * 32 + 4);
            unsigned lo = pack4_fp8(qclamp(a0.x, sf_x), qclamp(a0.y, sf_x),
                                    qclamp(a0.z, sf_x), qclamp(a0.w, sf_x));
            unsigned hi = pack4_fp8(qclamp(a1.x, sf_x), qclamp(a1.y, sf_x),
                                    qclamp(a1.z, sf_x), qclamp(a1.w, sf_x));
            ll A = (ll)lo | ((ll)hi << 32);
            #pragma unroll
            for (int j = 0; j < 4; ++j)
                acc[j] = __builtin_amdgcn_mfma_f32_16x16x32_fp8_fp8(
                    A, Breg[ks][j], acc[j], 0, 0, 0);
        }

        // C/D layout: col = lane&15, row = (lane>>4)*4 + r
        int crow = tile * 16 + kg * 4;
        int ccol = w * 64 + r16;
        #pragma unroll
        for (int j = 0; j < 4; ++j)
            #pragma unroll
            for (int r = 0; r < 4; ++r)
                C[(size_t)(crow + r) * 256 + ccol + j * 16] = acc[j][r] * outscale;
    }
}

// ---------------------------------------------------------------------------
extern "C" void kernel_launch(void* const* d_in, const int* in_sizes, int n_in,
                              void* d_out, int out_size, void* d_ws, size_t ws_size,
                              hipStream_t stream) {
    const float* x = (const float*)d_in[0];             // [8,8192,256] f32
    const float* k = (const float*)d_in[1];             // [256,256] f32
    const float* input_scale = (const float*)d_in[2];   // [1]
    const float* kernel_scale = (const float*)d_in[3];  // [1]
    float* out = (float*)d_out;

    unsigned* amax_bits = (unsigned*)d_ws;              // [0]=amax_x, [1]=amax_k
    ll* pack = (ll*)((char*)d_ws + 256);                // 64 KiB packed fp8 B

    int nx = in_sizes[0];                               // 16,777,216
    int nk = in_sizes[1];                               // 65,536
    int M = nx / 256;                                   // 65,536
    int ntiles = M / 16;                                // 4096

    hipMemsetAsync(d_ws, 0, 16, stream);
    amax2_kernel<<<XBLK + 32, 256, 0, stream>>>(x, (unsigned)(nx / 4),
                                                k, (unsigned)(nk / 4), amax_bits);
    pack_k_kernel<<<32, 256, 0, stream>>>(k, amax_bits, kernel_scale, pack);
    gemm_kernel<<<1024, 256, 0, stream>>>(x, pack, amax_bits, input_scale,
                                          kernel_scale, out, ntiles);
}

// Round 3
// 76.182 us; speedup vs baseline: 1.0799x; 1.0799x over previous
//
#include <hip/hip_runtime.h>
#include <stdint.h>

#define FP8_MAX 448.0f
#define NXB 2048  // x-amax blocks; block NXB handles k (amax + pack)

typedef __attribute__((ext_vector_type(4))) float f32x4;
typedef long long ll;

// flax fp8_ops.compute_scale: sf = fp8_max/amax with fallbacks (qdq multiplier).
__device__ __forceinline__ float scale_factor(float amax, float prev_scale) {
    float sf = FP8_MAX / amax;
    if (!(amax > 0.0f) || !isfinite(amax)) sf = 1.0f / prev_scale;
    return sf;
}

__device__ __forceinline__ unsigned pack4_fp8(float a, float b, float c, float d) {
    int v = __builtin_amdgcn_cvt_pk_fp8_f32(a, b, 0, false);
    v = __builtin_amdgcn_cvt_pk_fp8_f32(c, d, v, true);
    return (unsigned)v;
}

__device__ __forceinline__ float amax4(f32x4 v, float m) {
    float a0 = fmaxf(__builtin_fabsf(v.x), __builtin_fabsf(v.y));
    float a1 = fmaxf(__builtin_fabsf(v.z), __builtin_fabsf(v.w));
    return fmaxf(m, fmaxf(a0, a1));
}

// ---------------------------------------------------------------------------
// prep: blocks [0,NXB) -> x amax partials[NXB] (no atomics, no init needed).
//       block NXB     -> k amax (block-local) + quantize/pack k into MFMA
//                        B-fragment layout + store kamaxf for the epilogue.
// pack[kstep*1024 + ntile*64 + lane] byte j: col=ntile*16+(lane&15),
//                                            k = kstep*32+(lane>>4)*8+j
// ---------------------------------------------------------------------------
__global__ __launch_bounds__(256) void prep_kernel(
    const float* __restrict__ x, const float* __restrict__ k,
    const float* __restrict__ kernel_scale,
    float* __restrict__ partials, float* __restrict__ kamaxf,
    ll* __restrict__ pack) {
    __shared__ float sm[4];
    int tid = threadIdx.x;
    int lane = tid & 63, w = tid >> 6;

    if (blockIdx.x < NXB) {
        const f32x4* p = (const f32x4*)x;
        unsigned base = blockIdx.x * 256 + tid;
        float m = 0.0f;
        #pragma unroll
        for (int t = 0; t < 8; ++t)
            m = amax4(p[base + (unsigned)t * (NXB * 256)], m);
        #pragma unroll
        for (int off = 32; off; off >>= 1)
            m = fmaxf(m, __shfl_down(m, off, 64));
        if (lane == 0) sm[w] = m;
        __syncthreads();
        if (tid == 0)
            partials[blockIdx.x] = fmaxf(fmaxf(sm[0], sm[1]), fmaxf(sm[2], sm[3]));
    } else {
        // ---- k amax (single block over 256 KiB) ----
        const f32x4* p = (const f32x4*)k;
        float m = 0.0f;
        #pragma unroll 8
        for (int t = 0; t < 64; ++t)
            m = amax4(p[tid + t * 256], m);
        #pragma unroll
        for (int off = 32; off; off >>= 1)
            m = fmaxf(m, __shfl_down(m, off, 64));
        if (lane == 0) sm[w] = m;
        __syncthreads();
        float amax = fmaxf(fmaxf(sm[0], sm[1]), fmaxf(sm[2], sm[3]));
        if (tid == 0) kamaxf[0] = amax;
        float sf = scale_factor(amax, kernel_scale[0]);
        // ---- pack: 8192 words, 32 per thread ----
        for (int i = 0; i < 32; ++i) {
            int t = tid + i * 256;
            int l = t & 63;
            int nt = (t >> 6) & 15;
            int kstep = t >> 10;
            int col = nt * 16 + (l & 15);
            int k0 = kstep * 32 + (l >> 4) * 8;
            float v[8];
            #pragma unroll
            for (int j = 0; j < 8; ++j)
                v[j] = k[(k0 + j) * 256 + col] * sf;   // |v|<=448(1+eps): RTNE->448
            unsigned lo = pack4_fp8(v[0], v[1], v[2], v[3]);
            unsigned hi = pack4_fp8(v[4], v[5], v[6], v[7]);
            pack[t] = (ll)lo | ((ll)hi << 32);
        }
    }
}

// ---------------------------------------------------------------------------
// GEMM: C[M,256] = qdq(x)[M,256] * qdq(k)[256,256] via fp8 MFMA.
// 1 block = one 16-row M-tile; 4 waves split N (64 cols each); wave's B slice
// (8 ks x 4 nt = 64 VGPR) preloaded; launch_bounds(256,4) keeps it resident.
// Each wave redundantly reduces amax_x from partials (L2-hot, ~40 inst).
// ---------------------------------------------------------------------------
__global__ __launch_bounds__(256, 4) void gemm_kernel(
    const float* __restrict__ x, const ll* __restrict__ Bpack,
    const float* __restrict__ partials, const float* __restrict__ kamaxf,
    const float* __restrict__ input_scale, const float* __restrict__ kernel_scale,
    float* __restrict__ C) {
    int w = threadIdx.x >> 6;
    int lane = threadIdx.x & 63;
    int kg = lane >> 4, r16 = lane & 15;

    // Issue B preload first so its latency hides under the reduce.
    ll Breg[8][4];
    #pragma unroll
    for (int ks = 0; ks < 8; ++ks)
        #pragma unroll
        for (int j = 0; j < 4; ++j)
            Breg[ks][j] = Bpack[ks * 1024 + (w * 4 + j) * 64 + lane];

    // amax_x = max over 2048 partials (each lane 8 x f32x4, then wave reduce).
    const f32x4* pp = (const f32x4*)partials;
    float m = 0.0f;
    #pragma unroll
    for (int i = 0; i < 8; ++i)
        m = amax4(pp[lane + i * 64], m);
    #pragma unroll
    for (int off = 32; off; off >>= 1)
        m = fmaxf(m, __shfl_xor(m, off, 64));
    float sf_x = scale_factor(m, input_scale[0]);
    float sf_k = scale_factor(kamaxf[0], kernel_scale[0]);
    float outscale = (1.0f / sf_x) * (1.0f / sf_k);

    const float* xp = x + (size_t)(blockIdx.x * 16 + r16) * 256 + kg * 8;
    f32x4 acc[4];
    #pragma unroll
    for (int j = 0; j < 4; ++j) acc[j] = (f32x4){0.f, 0.f, 0.f, 0.f};

    #pragma unroll
    for (int ks = 0; ks < 8; ++ks) {
        f32x4 a0 = *(const f32x4*)(xp + ks * 32);
        f32x4 a1 = *(const f32x4*)(xp + ks * 32 + 4);
        unsigned lo = pack4_fp8(a0.x * sf_x, a0.y * sf_x, a0.z * sf_x, a0.w * sf_x);
        unsigned hi = pack4_fp8(a1.x * sf_x, a1.y * sf_x, a1.z * sf_x, a1.w * sf_x);
        ll A = (ll)lo | ((ll)hi << 32);
        #pragma unroll
        for (int j = 0; j < 4; ++j)
            acc[j] = __builtin_amdgcn_mfma_f32_16x16x32_fp8_fp8(
                A, Breg[ks][j], acc[j], 0, 0, 0);
    }

    // C/D layout: col = lane&15, row = (lane>>4)*4 + r
    int crow = blockIdx.x * 16 + kg * 4;
    int ccol = w * 64 + r16;
    #pragma unroll
    for (int j = 0; j < 4; ++j)
        #pragma unroll
        for (int r = 0; r < 4; ++r)
            C[(size_t)(crow + r) * 256 + ccol + j * 16] = acc[j][r] * outscale;
}

// ---------------------------------------------------------------------------
extern "C" void kernel_launch(void* const* d_in, const int* in_sizes, int n_in,
                              void* d_out, int out_size, void* d_ws, size_t ws_size,
                              hipStream_t stream) {
    const float* x = (const float*)d_in[0];             // [8,8192,256] f32
    const float* k = (const float*)d_in[1];             // [256,256] f32
    const float* input_scale = (const float*)d_in[2];   // [1]
    const float* kernel_scale = (const float*)d_in[3];  // [1]
    float* out = (float*)d_out;

    float* partials = (float*)d_ws;                     // [2048]
    float* kamaxf = partials + 2048;                    // [1]
    ll* pack = (ll*)((char*)d_ws + 16384);              // 64 KiB packed fp8 B

    int nx = in_sizes[0];                               // 16,777,216
    int M = nx / 256;                                   // 65,536 rows
    int ntiles = M / 16;                                // 4096

    prep_kernel<<<NXB + 1, 256, 0, stream>>>(x, k, kernel_scale,
                                             partials, kamaxf, pack);
    gemm_kernel<<<ntiles, 256, 0, stream>>>(x, pack, partials, kamaxf,
                                            input_scale, kernel_scale, out);
}

// Round 4
// 63.937 us; speedup vs baseline: 1.2868x; 1.1915x over previous
//
#include <hip/hip_runtime.h>
#include <stdint.h>

#define FP8_MAX 448.0f
#define NXB 2048  // x-amax blocks (blockIdx 1..NXB); blockIdx 0 does k amax+pack

typedef __attribute__((ext_vector_type(4))) float f32x4;
typedef long long ll;

// flax fp8_ops.compute_scale: sf = fp8_max/amax with fallbacks (qdq multiplier).
__device__ __forceinline__ float scale_factor(float amax, float prev_scale) {
    float sf = FP8_MAX / amax;
    if (!(amax > 0.0f) || !isfinite(amax)) sf = 1.0f / prev_scale;
    return sf;
}

__device__ __forceinline__ unsigned pack4_fp8(float a, float b, float c, float d) {
    int v = __builtin_amdgcn_cvt_pk_fp8_f32(a, b, 0, false);
    v = __builtin_amdgcn_cvt_pk_fp8_f32(c, d, v, true);
    return (unsigned)v;
}

__device__ __forceinline__ float amax4(f32x4 v, float m) {
    float a0 = fmaxf(__builtin_fabsf(v.x), __builtin_fabsf(v.y));
    float a1 = fmaxf(__builtin_fabsf(v.z), __builtin_fabsf(v.w));
    return fmaxf(m, fmaxf(a0, a1));
}

// ---------------------------------------------------------------------------
// prep: block 0        -> k amax (block-local) + quantize/pack k into MFMA
//                         B-fragment layout + store kamaxf. (dispatched first
//                         so its long single-block tail overlaps the x sweep)
//       blocks 1..NXB  -> x amax partials[NXB] (no atomics, no init needed).
// pack[kstep*1024 + ntile*64 + lane] byte j: col=ntile*16+(lane&15),
//                                            k = kstep*32+(lane>>4)*8+j
// ---------------------------------------------------------------------------
__global__ __launch_bounds__(256) void prep_kernel(
    const float* __restrict__ x, const float* __restrict__ k,
    const float* __restrict__ kernel_scale,
    float* __restrict__ partials, float* __restrict__ kamaxf,
    ll* __restrict__ pack) {
    __shared__ float sm[4];
    int tid = threadIdx.x;
    int lane = tid & 63, w = tid >> 6;

    if (blockIdx.x != 0) {
        const f32x4* p = (const f32x4*)x;
        unsigned base = (blockIdx.x - 1) * 256 + tid;
        float m = 0.0f;
        #pragma unroll
        for (int t = 0; t < 8; ++t)
            m = amax4(p[base + (unsigned)t * (NXB * 256)], m);
        #pragma unroll
        for (int off = 32; off; off >>= 1)
            m = fmaxf(m, __shfl_down(m, off, 64));
        if (lane == 0) sm[w] = m;
        __syncthreads();
        if (tid == 0)
            partials[blockIdx.x - 1] =
                fmaxf(fmaxf(sm[0], sm[1]), fmaxf(sm[2], sm[3]));
    } else {
        // ---- k amax (single block over 256 KiB) ----
        const f32x4* p = (const f32x4*)k;
        float m = 0.0f;
        #pragma unroll 8
        for (int t = 0; t < 64; ++t)
            m = amax4(p[tid + t * 256], m);
        #pragma unroll
        for (int off = 32; off; off >>= 1)
            m = fmaxf(m, __shfl_down(m, off, 64));
        if (lane == 0) sm[w] = m;
        __syncthreads();
        float amax = fmaxf(fmaxf(sm[0], sm[1]), fmaxf(sm[2], sm[3]));
        if (tid == 0) kamaxf[0] = amax;
        float sf = scale_factor(amax, kernel_scale[0]);
        // ---- pack: 8192 words, 32 per thread ----
        for (int i = 0; i < 32; ++i) {
            int t = tid + i * 256;
            int l = t & 63;
            int nt = (t >> 6) & 15;
            int kstep = t >> 10;
            int col = nt * 16 + (l & 15);
            int k0 = kstep * 32 + (l >> 4) * 8;
            float v[8];
            #pragma unroll
            for (int j = 0; j < 8; ++j)
                v[j] = k[(k0 + j) * 256 + col] * sf;  // |v|<=448(1+eps): RTNE->448
            unsigned lo = pack4_fp8(v[0], v[1], v[2], v[3]);
            unsigned hi = pack4_fp8(v[4], v[5], v[6], v[7]);
            pack[t] = (ll)lo | ((ll)hi << 32);
        }
    }
}

// ---------------------------------------------------------------------------
// GEMM: C[M,256] = qdq(x)[M,256] * qdq(k)[256,256] via fp8 MFMA.
// Block = 64 rows, 4 waves; wave w owns N-quarter [w*64, w*64+64).
// Wave's B slice (8ks x 4nt = 32 ll = 64 VGPR) loaded once, REUSED by 4
// row-groups -> compiler must keep it resident. Per row-group: all 16 x-loads
// issued as a batch (deep vmcnt pipeline), quant, 32 MFMA, store.
// launch_bounds(256,2): 256-VGPR budget, ILP over TLP.
// ---------------------------------------------------------------------------
__global__ __launch_bounds__(256, 2) void gemm_kernel(
    const float* __restrict__ x, const ll* __restrict__ Bpack,
    const float* __restrict__ partials, const float* __restrict__ kamaxf,
    const float* __restrict__ input_scale, const float* __restrict__ kernel_scale,
    float* __restrict__ C) {
    int w = threadIdx.x >> 6;
    int lane = threadIdx.x & 63;
    int kg = lane >> 4, r16 = lane & 15;

    // B fragments: issued first so latency hides under the amax reduce.
    ll Breg[32];  // [ks*4+j]
    #pragma unroll
    for (int i = 0; i < 32; ++i)
        Breg[i] = Bpack[(i >> 2) * 1024 + (w * 4 + (i & 3)) * 64 + lane];

    // amax_x = max over 2048 partials (L2-hot): 8 f32x4/lane + wave reduce.
    const f32x4* pp = (const f32x4*)partials;
    float m = 0.0f;
    #pragma unroll
    for (int i = 0; i < 8; ++i)
        m = amax4(pp[lane + i * 64], m);
    #pragma unroll
    for (int off = 32; off; off >>= 1)
        m = fmaxf(m, __shfl_xor(m, off, 64));
    float sf_x = scale_factor(m, input_scale[0]);
    float sf_k = scale_factor(kamaxf[0], kernel_scale[0]);
    float outscale = (1.0f / sf_x) * (1.0f / sf_k);

    const float* xbase = x + (size_t)blockIdx.x * 64 * 256;
    float* cbase = C + (size_t)blockIdx.x * 64 * 256 + w * 64;

    #pragma unroll
    for (int rg = 0; rg < 4; ++rg) {
        const float* xp = xbase + (rg * 16 + r16) * 256 + kg * 8;
        // Batch-load this row-group's A operands (16 independent f32x4 loads).
        f32x4 raw[8][2];
        #pragma unroll
        for (int ks = 0; ks < 8; ++ks) {
            raw[ks][0] = *(const f32x4*)(xp + ks * 32);
            raw[ks][1] = *(const f32x4*)(xp + ks * 32 + 4);
        }
        ll A[8];
        #pragma unroll
        for (int ks = 0; ks < 8; ++ks) {
            f32x4 a0 = raw[ks][0], a1 = raw[ks][1];
            unsigned lo = pack4_fp8(a0.x * sf_x, a0.y * sf_x, a0.z * sf_x, a0.w * sf_x);
            unsigned hi = pack4_fp8(a1.x * sf_x, a1.y * sf_x, a1.z * sf_x, a1.w * sf_x);
            A[ks] = (ll)lo | ((ll)hi << 32);
        }
        f32x4 acc[4];
        #pragma unroll
        for (int j = 0; j < 4; ++j) acc[j] = (f32x4){0.f, 0.f, 0.f, 0.f};
        #pragma unroll
        for (int ks = 0; ks < 8; ++ks)
            #pragma unroll
            for (int j = 0; j < 4; ++j)
                acc[j] = __builtin_amdgcn_mfma_f32_16x16x32_fp8_fp8(
                    A[ks], Breg[ks * 4 + j], acc[j], 0, 0, 0);

        // C/D layout: col = lane&15, row = (lane>>4)*4 + r
        int crow = rg * 16 + kg * 4;
        #pragma unroll
        for (int j = 0; j < 4; ++j)
            #pragma unroll
            for (int r = 0; r < 4; ++r)
                cbase[(size_t)(crow + r) * 256 + j * 16 + r16] = acc[j][r] * outscale;
    }
}

// ---------------------------------------------------------------------------
extern "C" void kernel_launch(void* const* d_in, const int* in_sizes, int n_in,
                              void* d_out, int out_size, void* d_ws, size_t ws_size,
                              hipStream_t stream) {
    const float* x = (const float*)d_in[0];             // [8,8192,256] f32
    const float* k = (const float*)d_in[1];             // [256,256] f32
    const float* input_scale = (const float*)d_in[2];   // [1]
    const float* kernel_scale = (const float*)d_in[3];  // [1]
    float* out = (float*)d_out;

    float* partials = (float*)d_ws;                     // [2048]
    float* kamaxf = partials + 2048;                    // [1]
    ll* pack = (ll*)((char*)d_ws + 16384);              // 64 KiB packed fp8 B

    int nx = in_sizes[0];                               // 16,777,216
    int M = nx / 256;                                   // 65,536 rows

    prep_kernel<<<NXB + 1, 256, 0, stream>>>(x, k, kernel_scale,
                                             partials, kamaxf, pack);
    gemm_kernel<<<M / 64, 256, 0, stream>>>(x, pack, partials, kamaxf,
                                            input_scale, kernel_scale, out);
}

// Round 5
// 48.196 us; speedup vs baseline: 1.7070x; 1.3266x over previous
//
#include <hip/hip_runtime.h>
#include <stdint.h>

#define FP8_MAX 448.0f
#define NXB 2048  // x-amax blocks (blockIdx 1..NXB); blockIdx 0 does k amax+pack

typedef __attribute__((ext_vector_type(4))) float f32x4;
typedef long long ll;

// flax fp8_ops.compute_scale: sf = fp8_max/amax with fallbacks (qdq multiplier).
__device__ __forceinline__ float scale_factor(float amax, float prev_scale) {
    float sf = FP8_MAX / amax;
    if (!(amax > 0.0f) || !isfinite(amax)) sf = 1.0f / prev_scale;
    return sf;
}

__device__ __forceinline__ unsigned pack4_fp8(float a, float b, float c, float d) {
    int v = __builtin_amdgcn_cvt_pk_fp8_f32(a, b, 0, false);
    v = __builtin_amdgcn_cvt_pk_fp8_f32(c, d, v, true);
    return (unsigned)v;
}

__device__ __forceinline__ float amax4(f32x4 v, float m) {
    float a0 = fmaxf(__builtin_fabsf(v.x), __builtin_fabsf(v.y));
    float a1 = fmaxf(__builtin_fabsf(v.z), __builtin_fabsf(v.w));
    return fmaxf(m, fmaxf(a0, a1));
}

// ---------------------------------------------------------------------------
// prep: block 0        -> k amax + quantize/pack k into MFMA B-fragment layout.
//       blocks 1..NXB  -> x amax partials[NXB] (no atomics, no init needed).
// pack[kstep*1024 + ntile*64 + lane] byte j: col=ntile*16+(lane&15),
//                                            k = kstep*32+(lane>>4)*8+j
// ---------------------------------------------------------------------------
__global__ __launch_bounds__(256) void prep_kernel(
    const float* __restrict__ x, const float* __restrict__ k,
    const float* __restrict__ kernel_scale,
    float* __restrict__ partials, float* __restrict__ kamaxf,
    ll* __restrict__ pack) {
    __shared__ float sm[4];
    int tid = threadIdx.x;
    int lane = tid & 63, w = tid >> 6;

    if (blockIdx.x != 0) {
        const f32x4* p = (const f32x4*)x;
        unsigned base = (blockIdx.x - 1) * 256 + tid;
        float m = 0.0f;
        #pragma unroll
        for (int t = 0; t < 8; ++t)
            m = amax4(p[base + (unsigned)t * (NXB * 256)], m);
        #pragma unroll
        for (int off = 32; off; off >>= 1)
            m = fmaxf(m, __shfl_down(m, off, 64));
        if (lane == 0) sm[w] = m;
        __syncthreads();
        if (tid == 0)
            partials[blockIdx.x - 1] =
                fmaxf(fmaxf(sm[0], sm[1]), fmaxf(sm[2], sm[3]));
    } else {
        // ---- k amax (single block over 256 KiB) ----
        const f32x4* p = (const f32x4*)k;
        float m = 0.0f;
        #pragma unroll 8
        for (int t = 0; t < 64; ++t)
            m = amax4(p[tid + t * 256], m);
        #pragma unroll
        for (int off = 32; off; off >>= 1)
            m = fmaxf(m, __shfl_down(m, off, 64));
        if (lane == 0) sm[w] = m;
        __syncthreads();
        float amax = fmaxf(fmaxf(sm[0], sm[1]), fmaxf(sm[2], sm[3]));
        if (tid == 0) kamaxf[0] = amax;
        float sf = scale_factor(amax, kernel_scale[0]);
        // ---- pack: 8192 words, 32 per thread ----
        for (int i = 0; i < 32; ++i) {
            int t = tid + i * 256;
            int l = t & 63;
            int nt = (t >> 6) & 15;
            int kstep = t >> 10;
            int col = nt * 16 + (l & 15);
            int k0 = kstep * 32 + (l >> 4) * 8;
            float v[8];
            #pragma unroll
            for (int j = 0; j < 8; ++j)
                v[j] = k[(k0 + j) * 256 + col] * sf;  // |v|<=448(1+eps): RTNE->448
            unsigned lo = pack4_fp8(v[0], v[1], v[2], v[3]);
            unsigned hi = pack4_fp8(v[4], v[5], v[6], v[7]);
            pack[t] = (ll)lo | ((ll)hi << 32);
        }
    }
}

// ---------------------------------------------------------------------------
// GEMM: C[M,256] = qdq(x)[M,256] * qdq(k)[256,256] via fp8 MFMA.
// Block = 32 rows, 4 waves; wave w owns N-quarter [w*64, w*64+64).
// Stage: 8 pinned (asm volatile) coalesced global_load_dwordx4 per thread
// (32KB f32 tile, linear), quantize in-reg -> fp8 tile in LDS (XOR-swizzled,
// conflict-free). Compute: per row-group 8x ds_read_b64 A-frags + 32 MFMA;
// B slice (8ks x 4nt = 64 VGPR) resident, reused by both row-groups.
// ---------------------------------------------------------------------------
__global__ __launch_bounds__(256, 3) void gemm_kernel(
    const float* __restrict__ x, const ll* __restrict__ Bpack,
    const float* __restrict__ partials, const float* __restrict__ kamaxf,
    const float* __restrict__ input_scale, const float* __restrict__ kernel_scale,
    float* __restrict__ C) {
    __shared__ char ldsc[32 * 256];  // 8KB fp8 tile, swizzled rows

    int tid = threadIdx.x;
    int w = tid >> 6;
    int lane = tid & 63;
    int kg = lane >> 4, r16 = lane & 15;

    // (1) issue the tile's 8 coalesced loads FIRST, pinned so they can't sink.
    const float* xt = x + (size_t)blockIdx.x * 32 * 256;
    f32x4 raw[8];
    #pragma unroll
    for (int i = 0; i < 8; ++i) {
        const float* p = xt + i * 1024 + tid * 4;
        asm volatile("global_load_dwordx4 %0, %1, off"
                     : "=v"(raw[i]) : "v"(p) : "memory");
    }

    // (2) B fragments preload (reused by both row-groups).
    ll Breg[32];  // [ks*4+j]
    #pragma unroll
    for (int i = 0; i < 32; ++i)
        Breg[i] = Bpack[(i >> 2) * 1024 + (w * 4 + (i & 3)) * 64 + lane];

    // (3) amax_x from 2048 partials (L2-hot): 8 f32x4/lane + wave reduce.
    const f32x4* pp = (const f32x4*)partials;
    float m = 0.0f;
    #pragma unroll
    for (int i = 0; i < 8; ++i)
        m = amax4(pp[lane + i * 64], m);
    #pragma unroll
    for (int off = 32; off; off >>= 1)
        m = fmaxf(m, __shfl_xor(m, off, 64));
    float sf_x = scale_factor(m, input_scale[0]);
    float sf_k = scale_factor(kamaxf[0], kernel_scale[0]);
    float outscale = (1.0f / sf_x) * (1.0f / sf_k);

    // (4) drain loads, quantize, swizzled LDS write.
    asm volatile("s_waitcnt vmcnt(0)" ::: "memory");
    __builtin_amdgcn_sched_barrier(0);
    #pragma unroll
    for (int i = 0; i < 8; ++i) {
        int row = i * 4 + w;           // bijective over 0..31
        int col = lane * 4;
        unsigned v = pack4_fp8(raw[i].x * sf_x, raw[i].y * sf_x,
                               raw[i].z * sf_x, raw[i].w * sf_x);
        *(unsigned*)&ldsc[row * 256 + (col ^ ((row & 15) << 3))] = v;
    }
    __syncthreads();

    // (5) compute + store.
    float* cbase = C + (size_t)blockIdx.x * 32 * 256 + w * 64;
    #pragma unroll
    for (int rg = 0; rg < 2; ++rg) {
        int row = rg * 16 + r16;
        unsigned rbase = (unsigned)row * 256;
        unsigned sw = (unsigned)(r16 << 3);
        ll A[8];
        #pragma unroll
        for (int ks = 0; ks < 8; ++ks)
            A[ks] = *(const ll*)&ldsc[rbase + (((unsigned)(kg * 8 + ks * 32)) ^ sw)];

        f32x4 acc[4];
        #pragma unroll
        for (int j = 0; j < 4; ++j) acc[j] = (f32x4){0.f, 0.f, 0.f, 0.f};
        #pragma unroll
        for (int ks = 0; ks < 8; ++ks)
            #pragma unroll
            for (int j = 0; j < 4; ++j)
                acc[j] = __builtin_amdgcn_mfma_f32_16x16x32_fp8_fp8(
                    A[ks], Breg[ks * 4 + j], acc[j], 0, 0, 0);

        // C/D layout: col = lane&15, row = (lane>>4)*4 + r
        int crow = rg * 16 + kg * 4;
        #pragma unroll
        for (int j = 0; j < 4; ++j)
            #pragma unroll
            for (int r = 0; r < 4; ++r)
                cbase[(size_t)(crow + r) * 256 + j * 16 + r16] =
                    acc[j][r] * outscale;
    }
}

// ---------------------------------------------------------------------------
extern "C" void kernel_launch(void* const* d_in, const int* in_sizes, int n_in,
                              void* d_out, int out_size, void* d_ws, size_t ws_size,
                              hipStream_t stream) {
    const float* x = (const float*)d_in[0];             // [8,8192,256] f32
    const float* k = (const float*)d_in[1];             // [256,256] f32
    const float* input_scale = (const float*)d_in[2];   // [1]
    const float* kernel_scale = (const float*)d_in[3];  // [1]
    float* out = (float*)d_out;

    float* partials = (float*)d_ws;                     // [2048]
    float* kamaxf = partials + 2048;                    // [1]
    ll* pack = (ll*)((char*)d_ws + 16384);              // 64 KiB packed fp8 B

    int nx = in_sizes[0];                               // 16,777,216
    int M = nx / 256;                                   // 65,536 rows

    prep_kernel<<<NXB + 1, 256, 0, stream>>>(x, k, kernel_scale,
                                             partials, kamaxf, pack);
    gemm_kernel<<<M / 32, 256, 0, stream>>>(x, pack, partials, kamaxf,
                                            input_scale, kernel_scale, out);
}

// Round 6
// 47.211 us; speedup vs baseline: 1.7426x; 1.0209x over previous
//
#include <hip/hip_runtime.h>
#include <stdint.h>

#define FP8_MAX 448.0f
#define NXB 2048  // x-amax blocks (blockIdx 1..NXB); blockIdx 0 does k amax+pack

typedef __attribute__((ext_vector_type(4))) float f32x4;
typedef long long ll;

// flax fp8_ops.compute_scale: sf = fp8_max/amax with fallbacks (qdq multiplier).
__device__ __forceinline__ float scale_factor(float amax, float prev_scale) {
    float sf = FP8_MAX / amax;
    if (!(amax > 0.0f) || !isfinite(amax)) sf = 1.0f / prev_scale;
    return sf;
}

__device__ __forceinline__ unsigned pack4_fp8(float a, float b, float c, float d) {
    int v = __builtin_amdgcn_cvt_pk_fp8_f32(a, b, 0, false);
    v = __builtin_amdgcn_cvt_pk_fp8_f32(c, d, v, true);
    return (unsigned)v;
}

__device__ __forceinline__ float amax4(f32x4 v, float m) {
    float a0 = fmaxf(__builtin_fabsf(v.x), __builtin_fabsf(v.y));
    float a1 = fmaxf(__builtin_fabsf(v.z), __builtin_fabsf(v.w));
    return fmaxf(m, fmaxf(a0, a1));
}

// ---------------------------------------------------------------------------
// prep: block 0        -> k amax + quantize/pack k into MFMA B-fragment layout.
//       blocks 1..NXB  -> x amax partials[NXB] (no atomics, no init needed).
// pack[kstep*1024 + ntile*64 + lane] byte j: col=ntile*16+(lane&15),
//                                            k = kstep*32+(lane>>4)*8+j
// ---------------------------------------------------------------------------
__global__ __launch_bounds__(256) void prep_kernel(
    const float* __restrict__ x, const float* __restrict__ k,
    const float* __restrict__ kernel_scale,
    float* __restrict__ partials, float* __restrict__ kamaxf,
    ll* __restrict__ pack) {
    __shared__ float sm[4];
    int tid = threadIdx.x;
    int lane = tid & 63, w = tid >> 6;

    if (blockIdx.x != 0) {
        const f32x4* p = (const f32x4*)x;
        unsigned base = (blockIdx.x - 1) * 256 + tid;
        float m = 0.0f;
        #pragma unroll
        for (int t = 0; t < 8; ++t)
            m = amax4(p[base + (unsigned)t * (NXB * 256)], m);
        #pragma unroll
        for (int off = 32; off; off >>= 1)
            m = fmaxf(m, __shfl_down(m, off, 64));
        if (lane == 0) sm[w] = m;
        __syncthreads();
        if (tid == 0)
            partials[blockIdx.x - 1] =
                fmaxf(fmaxf(sm[0], sm[1]), fmaxf(sm[2], sm[3]));
    } else {
        // ---- k amax (single block over 256 KiB) ----
        const f32x4* p = (const f32x4*)k;
        float m = 0.0f;
        #pragma unroll 8
        for (int t = 0; t < 64; ++t)
            m = amax4(p[tid + t * 256], m);
        #pragma unroll
        for (int off = 32; off; off >>= 1)
            m = fmaxf(m, __shfl_down(m, off, 64));
        if (lane == 0) sm[w] = m;
        __syncthreads();
        float amax = fmaxf(fmaxf(sm[0], sm[1]), fmaxf(sm[2], sm[3]));
        if (tid == 0) kamaxf[0] = amax;
        float sf = scale_factor(amax, kernel_scale[0]);
        // ---- pack: 8192 words, 32 per thread ----
        for (int i = 0; i < 32; ++i) {
            int t = tid + i * 256;
            int l = t & 63;
            int nt = (t >> 6) & 15;
            int kstep = t >> 10;
            int col = nt * 16 + (l & 15);
            int k0 = kstep * 32 + (l >> 4) * 8;
            float v[8];
            #pragma unroll
            for (int j = 0; j < 8; ++j)
                v[j] = k[(k0 + j) * 256 + col] * sf;  // |v|<=448(1+eps): RTNE->448
            unsigned lo = pack4_fp8(v[0], v[1], v[2], v[3]);
            unsigned hi = pack4_fp8(v[4], v[5], v[6], v[7]);
            pack[t] = (ll)lo | ((ll)hi << 32);
        }
    }
}

// ---------------------------------------------------------------------------
// GEMM: C[M,256] = qdq(x)[M,256] * qdq(k)[256,256] via fp8 MFMA.
// Persistent-ish: grid 512 (2 blocks/CU co-resident), each block = 4 tiles of
// 32 rows. B slice + amax reduce paid once per block. Tiles software-pipelined:
// issue pinned loads(t+1) -> s_waitcnt vmcnt(8) (t's loads drained, t+1's stay
// in flight ACROSS the barrier) -> quant->LDS (dbuf, XOR swizzle) ->
// lgkmcnt(0) + raw s_barrier (NOT __syncthreads: that drains vmcnt) ->
// 64 MFMA -> stores.
// ---------------------------------------------------------------------------
#define ISSUE(RAW, t)                                                          \
    do {                                                                       \
        _Pragma("unroll")                                                      \
        for (int i = 0; i < 8; ++i) {                                          \
            const float* p = xt + (t) * 8192 + i * 1024 + tid * 4;             \
            asm volatile("global_load_dwordx4 %0, %1, off"                     \
                         : "=v"(RAW[i]) : "v"(p) : "memory");                  \
        }                                                                      \
    } while (0)

#define TILE(RAW, b, t)                                                        \
    do {                                                                       \
        _Pragma("unroll")                                                      \
        for (int i = 0; i < 8; ++i) {                                          \
            int row = i * 4 + w;                                               \
            unsigned v = pack4_fp8(RAW[i].x * sf_x, RAW[i].y * sf_x,           \
                                   RAW[i].z * sf_x, RAW[i].w * sf_x);          \
            *(unsigned*)&lds[b][row * 256 + ((lane * 4) ^ ((row & 15) << 3))] = v; \
        }                                                                      \
        asm volatile("s_waitcnt lgkmcnt(0)" ::: "memory");                     \
        __builtin_amdgcn_s_barrier();                                          \
        __builtin_amdgcn_sched_barrier(0);                                     \
        _Pragma("unroll")                                                      \
        for (int rg = 0; rg < 2; ++rg) {                                       \
            unsigned rbase = (unsigned)((rg * 16 + r16) * 256);                \
            ll A[8];                                                           \
            _Pragma("unroll")                                                  \
            for (int ks = 0; ks < 8; ++ks)                                     \
                A[ks] = *(const ll*)&lds[b][rbase +                            \
                        (((unsigned)(kg * 8 + ks * 32)) ^ sw)];                \
            f32x4 acc[4];                                                      \
            _Pragma("unroll")                                                  \
            for (int j = 0; j < 4; ++j) acc[j] = (f32x4){0.f, 0.f, 0.f, 0.f};  \
            _Pragma("unroll")                                                  \
            for (int ks = 0; ks < 8; ++ks)                                     \
                _Pragma("unroll")                                              \
                for (int j = 0; j < 4; ++j)                                    \
                    acc[j] = __builtin_amdgcn_mfma_f32_16x16x32_fp8_fp8(       \
                        A[ks], Breg[ks * 4 + j], acc[j], 0, 0, 0);             \
            int crow = rg * 16 + kg * 4;                                       \
            _Pragma("unroll")                                                  \
            for (int j = 0; j < 4; ++j)                                        \
                _Pragma("unroll")                                              \
                for (int r = 0; r < 4; ++r)                                    \
                    cb[(size_t)(t) * 8192 + (size_t)(crow + r) * 256 +         \
                       j * 16 + r16] = acc[j][r] * outscale;                   \
        }                                                                      \
    } while (0)

__global__ __launch_bounds__(256, 2) void gemm_kernel(
    const float* __restrict__ x, const ll* __restrict__ Bpack,
    const float* __restrict__ partials, const float* __restrict__ kamaxf,
    const float* __restrict__ input_scale, const float* __restrict__ kernel_scale,
    float* __restrict__ C) {
    __shared__ char lds[2][32 * 256];  // double-buffered fp8 tiles

    int tid = threadIdx.x;
    int w = tid >> 6;
    int lane = tid & 63;
    int kg = lane >> 4, r16 = lane & 15;
    unsigned sw = (unsigned)(r16 << 3);

    // Compiler-visible preamble FIRST (so its counted waits stay correct
    // before any opaque asm loads are in flight).
    ll Breg[32];  // [ks*4+j]
    #pragma unroll
    for (int i = 0; i < 32; ++i)
        Breg[i] = Bpack[(i >> 2) * 1024 + (w * 4 + (i & 3)) * 64 + lane];

    const f32x4* pp = (const f32x4*)partials;
    float m = 0.0f;
    #pragma unroll
    for (int i = 0; i < 8; ++i)
        m = amax4(pp[lane + i * 64], m);
    #pragma unroll
    for (int off = 32; off; off >>= 1)
        m = fmaxf(m, __shfl_xor(m, off, 64));
    float sf_x = scale_factor(m, input_scale[0]);
    float sf_k = scale_factor(kamaxf[0], kernel_scale[0]);
    float outscale = (1.0f / sf_x) * (1.0f / sf_k);

    const float* xt = x + (size_t)blockIdx.x * 128 * 256;
    float* cb = C + (size_t)blockIdx.x * 128 * 256 + w * 64;

    f32x4 rawA[8], rawB[8];

    ISSUE(rawA, 0);

    // t0
    ISSUE(rawB, 1);
    asm volatile("s_waitcnt vmcnt(8)" ::: "memory");
    __builtin_amdgcn_sched_barrier(0);
    TILE(rawA, 0, 0);

    // t1
    ISSUE(rawA, 2);
    asm volatile("s_waitcnt vmcnt(8)" ::: "memory");
    __builtin_amdgcn_sched_barrier(0);
    TILE(rawB, 1, 1);

    // t2
    ISSUE(rawB, 3);
    asm volatile("s_waitcnt vmcnt(8)" ::: "memory");
    __builtin_amdgcn_sched_barrier(0);
    TILE(rawA, 0, 2);

    // t3
    asm volatile("s_waitcnt vmcnt(0)" ::: "memory");
    __builtin_amdgcn_sched_barrier(0);
    TILE(rawB, 1, 3);
}

// ---------------------------------------------------------------------------
extern "C" void kernel_launch(void* const* d_in, const int* in_sizes, int n_in,
                              void* d_out, int out_size, void* d_ws, size_t ws_size,
                              hipStream_t stream) {
    const float* x = (const float*)d_in[0];             // [8,8192,256] f32
    const float* k = (const float*)d_in[1];             // [256,256] f32
    const float* input_scale = (const float*)d_in[2];   // [1]
    const float* kernel_scale = (const float*)d_in[3];  // [1]
    float* out = (float*)d_out;

    float* partials = (float*)d_ws;                     // [2048]
    float* kamaxf = partials + 2048;                    // [1]
    ll* pack = (ll*)((char*)d_ws + 16384);              // 64 KiB packed fp8 B

    int nx = in_sizes[0];                               // 16,777,216
    int M = nx / 256;                                   // 65,536 rows

    prep_kernel<<<NXB + 1, 256, 0, stream>>>(x, k, kernel_scale,
                                             partials, kamaxf, pack);
    gemm_kernel<<<M / 128, 256, 0, stream>>>(x, pack, partials, kamaxf,
                                             input_scale, kernel_scale, out);
}

// Round 7
// 42.530 us; speedup vs baseline: 1.9345x; 1.1101x over previous
//
#include <hip/hip_runtime.h>
#include <stdint.h>

#define FP8_MAX 448.0f
#define KBLK 16   // k amax+pack blocks (blockIdx 0..15)
#define NXB 2048  // x-amax blocks (blockIdx KBLK .. KBLK+NXB-1)

typedef __attribute__((ext_vector_type(4))) float f32x4;
typedef long long ll;

// flax fp8_ops.compute_scale: sf = fp8_max/amax with fallbacks (qdq multiplier).
__device__ __forceinline__ float scale_factor(float amax, float prev_scale) {
    float sf = FP8_MAX / amax;
    if (!(amax > 0.0f) || !isfinite(amax)) sf = 1.0f / prev_scale;
    return sf;
}

__device__ __forceinline__ unsigned pack4_fp8(float a, float b, float c, float d) {
    int v = __builtin_amdgcn_cvt_pk_fp8_f32(a, b, 0, false);
    v = __builtin_amdgcn_cvt_pk_fp8_f32(c, d, v, true);
    return (unsigned)v;
}

__device__ __forceinline__ float amax4(f32x4 v, float m) {
    float a0 = fmaxf(__builtin_fabsf(v.x), __builtin_fabsf(v.y));
    float a1 = fmaxf(__builtin_fabsf(v.z), __builtin_fabsf(v.w));
    return fmaxf(m, fmaxf(a0, a1));
}

// ---------------------------------------------------------------------------
// prep: blocks 0..KBLK-1 -> EACH redundantly computes k amax (256KB, L2-shared,
//                          hidden under the x sweep) then packs 1/KBLK of the
//                          MFMA B-fragment buffer. No serial single-block tail.
//       blocks KBLK..    -> x amax partials[NXB] (no atomics, no init needed).
// pack[kstep*1024 + ntile*64 + lane] byte j: col=ntile*16+(lane&15),
//                                            k = kstep*32+(lane>>4)*8+j
// ---------------------------------------------------------------------------
__global__ __launch_bounds__(256) void prep_kernel(
    const float* __restrict__ x, const float* __restrict__ k,
    const float* __restrict__ kernel_scale,
    float* __restrict__ partials, float* __restrict__ kamaxf,
    ll* __restrict__ pack) {
    __shared__ float sm[4];
    int tid = threadIdx.x;
    int lane = tid & 63, w = tid >> 6;

    if (blockIdx.x >= KBLK) {
        const f32x4* p = (const f32x4*)x;
        unsigned base = (blockIdx.x - KBLK) * 256 + tid;
        float m = 0.0f;
        #pragma unroll
        for (int t = 0; t < 8; ++t)
            m = amax4(p[base + (unsigned)t * (NXB * 256)], m);
        #pragma unroll
        for (int off = 32; off; off >>= 1)
            m = fmaxf(m, __shfl_down(m, off, 64));
        if (lane == 0) sm[w] = m;
        __syncthreads();
        if (tid == 0)
            partials[blockIdx.x - KBLK] =
                fmaxf(fmaxf(sm[0], sm[1]), fmaxf(sm[2], sm[3]));
    } else {
        // ---- k amax (redundant per block; 256 KiB, L2-broadcast) ----
        const f32x4* p = (const f32x4*)k;
        float m = 0.0f;
        #pragma unroll 8
        for (int t = 0; t < 64; ++t)
            m = amax4(p[tid + t * 256], m);
        #pragma unroll
        for (int off = 32; off; off >>= 1)
            m = fmaxf(m, __shfl_down(m, off, 64));
        if (lane == 0) sm[w] = m;
        __syncthreads();
        float amax = fmaxf(fmaxf(sm[0], sm[1]), fmaxf(sm[2], sm[3]));
        if (tid == 0) kamaxf[0] = amax;  // all KBLK blocks write same value
        float sf = scale_factor(amax, kernel_scale[0]);
        // ---- pack this block's slice: 512 of 8192 words ----
        #pragma unroll
        for (int ii = 0; ii < 2; ++ii) {
            int t = (blockIdx.x * 2 + ii) * 256 + tid;
            int l = t & 63;
            int nt = (t >> 6) & 15;
            int kstep = t >> 10;
            int col = nt * 16 + (l & 15);
            int k0 = kstep * 32 + (l >> 4) * 8;
            float v[8];
            #pragma unroll
            for (int j = 0; j < 8; ++j)
                v[j] = k[(k0 + j) * 256 + col] * sf;  // |v|<=448(1+eps): RTNE->448
            unsigned lo = pack4_fp8(v[0], v[1], v[2], v[3]);
            unsigned hi = pack4_fp8(v[4], v[5], v[6], v[7]);
            pack[t] = (ll)lo | ((ll)hi << 32);
        }
    }
}

// ---------------------------------------------------------------------------
// GEMM: C[M,256] = qdq(x)[M,256] * qdq(k)[256,256] via fp8 MFMA.
// Grid 512 (2 blocks/CU co-resident), each block = 4 tiles of 32 rows.
// B slice + amax reduce paid once per block. Tiles software-pipelined with
// COUNTED vmcnt that accounts for C-stores (stores increment vmcnt!):
//   steady state queue at tile t's wait: [raw_t(8), stores(t-1)(32), raw_t+1(8)]
//   -> vmcnt(40) drains exactly raw_t; never blocks on store acks.
// ---------------------------------------------------------------------------
#define ISSUE(RAW, t)                                                          \
    do {                                                                       \
        _Pragma("unroll")                                                      \
        for (int i = 0; i < 8; ++i) {                                          \
            const float* p = xt + (t) * 8192 + i * 1024 + tid * 4;             \
            asm volatile("global_load_dwordx4 %0, %1, off"                     \
                         : "=v"(RAW[i]) : "v"(p) : "memory");                  \
        }                                                                      \
    } while (0)

#define TILE(RAW, b, t)                                                        \
    do {                                                                       \
        _Pragma("unroll")                                                      \
        for (int i = 0; i < 8; ++i) {                                          \
            int row = i * 4 + w;                                               \
            unsigned v = pack4_fp8(RAW[i].x * sf_x, RAW[i].y * sf_x,           \
                                   RAW[i].z * sf_x, RAW[i].w * sf_x);          \
            *(unsigned*)&lds[b][row * 256 + ((lane * 4) ^ ((row & 15) << 3))] = v; \
        }                                                                      \
        asm volatile("s_waitcnt lgkmcnt(0)" ::: "memory");                     \
        __builtin_amdgcn_s_barrier();                                          \
        __builtin_amdgcn_sched_barrier(0);                                     \
        _Pragma("unroll")                                                      \
        for (int rg = 0; rg < 2; ++rg) {                                       \
            unsigned rbase = (unsigned)((rg * 16 + r16) * 256);                \
            ll A[8];                                                           \
            _Pragma("unroll")                                                  \
            for (int ks = 0; ks < 8; ++ks)                                     \
                A[ks] = *(const ll*)&lds[b][rbase +                            \
                        (((unsigned)(kg * 8 + ks * 32)) ^ sw)];                \
            f32x4 acc[4];                                                      \
            _Pragma("unroll")                                                  \
            for (int j = 0; j < 4; ++j) acc[j] = (f32x4){0.f, 0.f, 0.f, 0.f};  \
            _Pragma("unroll")                                                  \
            for (int ks = 0; ks < 8; ++ks)                                     \
                _Pragma("unroll")                                              \
                for (int j = 0; j < 4; ++j)                                    \
                    acc[j] = __builtin_amdgcn_mfma_f32_16x16x32_fp8_fp8(       \
                        A[ks], Breg[ks * 4 + j], acc[j], 0, 0, 0);             \
            int crow = rg * 16 + kg * 4;                                       \
            _Pragma("unroll")                                                  \
            for (int j = 0; j < 4; ++j)                                        \
                _Pragma("unroll")                                              \
                for (int r = 0; r < 4; ++r)                                    \
                    cb[(size_t)(t) * 8192 + (size_t)(crow + r) * 256 +         \
                       j * 16 + r16] = acc[j][r] * outscale;                   \
        }                                                                      \
    } while (0)

__global__ __launch_bounds__(256, 2) void gemm_kernel(
    const float* __restrict__ x, const ll* __restrict__ Bpack,
    const float* __restrict__ partials, const float* __restrict__ kamaxf,
    const float* __restrict__ input_scale, const float* __restrict__ kernel_scale,
    float* __restrict__ C) {
    __shared__ char lds[2][32 * 256];  // double-buffered fp8 tiles

    int tid = threadIdx.x;
    int w = tid >> 6;
    int lane = tid & 63;
    int kg = lane >> 4, r16 = lane & 15;
    unsigned sw = (unsigned)(r16 << 3);

    // Compiler-visible preamble FIRST (its counted waits stay correct before
    // any opaque asm loads are in flight).
    ll Breg[32];  // [ks*4+j]
    #pragma unroll
    for (int i = 0; i < 32; ++i)
        Breg[i] = Bpack[(i >> 2) * 1024 + (w * 4 + (i & 3)) * 64 + lane];

    const f32x4* pp = (const f32x4*)partials;
    float m = 0.0f;
    #pragma unroll
    for (int i = 0; i < 8; ++i)
        m = amax4(pp[lane + i * 64], m);
    #pragma unroll
    for (int off = 32; off; off >>= 1)
        m = fmaxf(m, __shfl_xor(m, off, 64));
    float sf_x = scale_factor(m, input_scale[0]);
    float sf_k = scale_factor(kamaxf[0], kernel_scale[0]);
    float outscale = (1.0f / sf_x) * (1.0f / sf_k);

    const float* xt = x + (size_t)blockIdx.x * 128 * 256;
    float* cb = C + (size_t)blockIdx.x * 128 * 256 + w * 64;

    f32x4 rawA[8], rawB[8];

    ISSUE(rawA, 0);

    // t0: queue [rawA(8), rawB(8)] -> drain rawA, keep rawB in flight.
    ISSUE(rawB, 1);
    asm volatile("s_waitcnt vmcnt(8)" ::: "memory");
    __builtin_amdgcn_sched_barrier(0);
    TILE(rawA, 0, 0);

    // t1: queue [rawB(8), stores_t0(32), rawA(8)] -> vmcnt(40) drains rawB only.
    ISSUE(rawA, 2);
    asm volatile("s_waitcnt vmcnt(40)" ::: "memory");
    __builtin_amdgcn_sched_barrier(0);
    TILE(rawB, 1, 1);

    // t2: queue [rawA(8), stores_t1(32), rawB(8)] -> vmcnt(40).
    ISSUE(rawB, 3);
    asm volatile("s_waitcnt vmcnt(40)" ::: "memory");
    __builtin_amdgcn_sched_barrier(0);
    TILE(rawA, 0, 2);

    // t3: queue [rawB(8), stores_t2(32)] -> vmcnt(32) drains rawB only.
    asm volatile("s_waitcnt vmcnt(32)" ::: "memory");
    __builtin_amdgcn_sched_barrier(0);
    TILE(rawB, 1, 3);
}

// ---------------------------------------------------------------------------
extern "C" void kernel_launch(void* const* d_in, const int* in_sizes, int n_in,
                              void* d_out, int out_size, void* d_ws, size_t ws_size,
                              hipStream_t stream) {
    const float* x = (const float*)d_in[0];             // [8,8192,256] f32
    const float* k = (const float*)d_in[1];             // [256,256] f32
    const float* input_scale = (const float*)d_in[2];   // [1]
    const float* kernel_scale = (const float*)d_in[3];  // [1]
    float* out = (float*)d_out;

    float* partials = (float*)d_ws;                     // [2048]
    float* kamaxf = partials + 2048;                    // [1]
    ll* pack = (ll*)((char*)d_ws + 16384);              // 64 KiB packed fp8 B

    int nx = in_sizes[0];                               // 16,777,216
    int M = nx / 256;                                   // 65,536 rows

    prep_kernel<<<NXB + KBLK, 256, 0, stream>>>(x, k, kernel_scale,
                                                partials, kamaxf, pack);
    gemm_kernel<<<M / 128, 256, 0, stream>>>(x, pack, partials, kamaxf,
                                             input_scale, kernel_scale, out);
}

// Round 8
// 41.085 us; speedup vs baseline: 2.0025x; 1.0352x over previous
//
#include <hip/hip_runtime.h>
#include <stdint.h>

#define FP8_MAX 448.0f
#define KBLK 16   // k amax+pack blocks (blockIdx 0..15)
#define NXB 2048  // x-amax blocks (blockIdx KBLK .. KBLK+NXB-1)

typedef __attribute__((ext_vector_type(4))) float f32x4;
typedef long long ll;

// flax fp8_ops.compute_scale: sf = fp8_max/amax with fallbacks (qdq multiplier).
__device__ __forceinline__ float scale_factor(float amax, float prev_scale) {
    float sf = FP8_MAX / amax;
    if (!(amax > 0.0f) || !isfinite(amax)) sf = 1.0f / prev_scale;
    return sf;
}

__device__ __forceinline__ unsigned pack4_fp8(float a, float b, float c, float d) {
    int v = __builtin_amdgcn_cvt_pk_fp8_f32(a, b, 0, false);
    v = __builtin_amdgcn_cvt_pk_fp8_f32(c, d, v, true);
    return (unsigned)v;
}

__device__ __forceinline__ float amax4(f32x4 v, float m) {
    float a0 = fmaxf(__builtin_fabsf(v.x), __builtin_fabsf(v.y));
    float a1 = fmaxf(__builtin_fabsf(v.z), __builtin_fabsf(v.w));
    return fmaxf(m, fmaxf(a0, a1));
}

// ---------------------------------------------------------------------------
// prep: blocks 0..KBLK-1 -> EACH redundantly computes k amax (256KB, L2-shared)
//                          then packs 1/KBLK of the MFMA B-fragment buffer.
//       blocks KBLK..    -> x amax partials[NXB]. SLICE-ALIGNED: block KBLK+xb
//                          reads gemm-block (xb>>2)'s 128-row slice, quarter
//                          (xb&3) -> same-XCD L2 reuse under round-robin.
// pack[kstep*1024 + ntile*64 + lane] byte j: col=ntile*16+(lane&15),
//                                            k = kstep*32+(lane>>4)*8+j
// ---------------------------------------------------------------------------
__global__ __launch_bounds__(256) void prep_kernel(
    const float* __restrict__ x, const float* __restrict__ k,
    const float* __restrict__ kernel_scale,
    float* __restrict__ partials, float* __restrict__ kamaxf,
    ll* __restrict__ pack) {
    __shared__ float sm[4];
    int tid = threadIdx.x;
    int lane = tid & 63, w = tid >> 6;

    if (blockIdx.x >= KBLK) {
        unsigned xb = blockIdx.x - KBLK;
        const f32x4* p = (const f32x4*)x;
        unsigned base = (xb >> 2) * 8192 + (xb & 3) * 2048 + tid;
        float m = 0.0f;
        #pragma unroll
        for (int t = 0; t < 8; ++t)
            m = amax4(p[base + (unsigned)t * 256], m);
        #pragma unroll
        for (int off = 32; off; off >>= 1)
            m = fmaxf(m, __shfl_down(m, off, 64));
        if (lane == 0) sm[w] = m;
        __syncthreads();
        if (tid == 0)
            partials[xb] = fmaxf(fmaxf(sm[0], sm[1]), fmaxf(sm[2], sm[3]));
    } else {
        // ---- k amax (redundant per block; 256 KiB, L2-broadcast) ----
        const f32x4* p = (const f32x4*)k;
        float m = 0.0f;
        #pragma unroll 8
        for (int t = 0; t < 64; ++t)
            m = amax4(p[tid + t * 256], m);
        #pragma unroll
        for (int off = 32; off; off >>= 1)
            m = fmaxf(m, __shfl_down(m, off, 64));
        if (lane == 0) sm[w] = m;
        __syncthreads();
        float amax = fmaxf(fmaxf(sm[0], sm[1]), fmaxf(sm[2], sm[3]));
        if (tid == 0) kamaxf[0] = amax;  // all KBLK blocks write same value
        float sf = scale_factor(amax, kernel_scale[0]);
        // ---- pack this block's slice: 512 of 8192 words ----
        #pragma unroll
        for (int ii = 0; ii < 2; ++ii) {
            int t = (blockIdx.x * 2 + ii) * 256 + tid;
            int l = t & 63;
            int nt = (t >> 6) & 15;
            int kstep = t >> 10;
            int col = nt * 16 + (l & 15);
            int k0 = kstep * 32 + (l >> 4) * 8;
            float v[8];
            #pragma unroll
            for (int j = 0; j < 8; ++j)
                v[j] = k[(k0 + j) * 256 + col] * sf;  // |v|<=448(1+eps): RTNE->448
            unsigned lo = pack4_fp8(v[0], v[1], v[2], v[3]);
            unsigned hi = pack4_fp8(v[4], v[5], v[6], v[7]);
            pack[t] = (ll)lo | ((ll)hi << 32);
        }
    }
}

// ---------------------------------------------------------------------------
// GEMM: C[M,256] = qdq(x)[M,256] * qdq(k)[256,256] via fp8 MFMA.
// Grid 512 (2 blocks/CU), 4 tiles of 32 rows per block, DEPTH-2 prefetch:
// 3 register buffers; issue t0,t1,t2 up front. In-order vmcnt accounting
// (issue positions raw0 1-8, raw1 9-16, raw2 17-24, stores0 25-56,
//  raw3 57-64, stores1 65-96) -> waits 16, 48, 40, 32: each drains exactly
// the tile it needs, leaves newer prefetches + store acks in flight.
// ---------------------------------------------------------------------------
#define ISSUE(RAW, t)                                                          \
    do {                                                                       \
        _Pragma("unroll")                                                      \
        for (int i = 0; i < 8; ++i) {                                          \
            const float* p = xt + (t) * 8192 + i * 1024 + tid * 4;             \
            asm volatile("global_load_dwordx4 %0, %1, off"                     \
                         : "=v"(RAW[i]) : "v"(p) : "memory");                  \
        }                                                                      \
    } while (0)

#define TILE(RAW, b, t)                                                        \
    do {                                                                       \
        _Pragma("unroll")                                                      \
        for (int i = 0; i < 8; ++i) {                                          \
            int row = i * 4 + w;                                               \
            unsigned v = pack4_fp8(RAW[i].x * sf_x, RAW[i].y * sf_x,           \
                                   RAW[i].z * sf_x, RAW[i].w * sf_x);          \
            *(unsigned*)&lds[b][row * 256 + ((lane * 4) ^ ((row & 15) << 3))] = v; \
        }                                                                      \
        asm volatile("s_waitcnt lgkmcnt(0)" ::: "memory");                     \
        __builtin_amdgcn_s_barrier();                                          \
        __builtin_amdgcn_sched_barrier(0);                                     \
        _Pragma("unroll")                                                      \
        for (int rg = 0; rg < 2; ++rg) {                                       \
            unsigned rbase = (unsigned)((rg * 16 + r16) * 256);                \
            ll A[8];                                                           \
            _Pragma("unroll")                                                  \
            for (int ks = 0; ks < 8; ++ks)                                     \
                A[ks] = *(const ll*)&lds[b][rbase +                            \
                        (((unsigned)(kg * 8 + ks * 32)) ^ sw)];                \
            f32x4 acc[4];                                                      \
            _Pragma("unroll")                                                  \
            for (int j = 0; j < 4; ++j) acc[j] = (f32x4){0.f, 0.f, 0.f, 0.f};  \
            _Pragma("unroll")                                                  \
            for (int ks = 0; ks < 8; ++ks)                                     \
                _Pragma("unroll")                                              \
                for (int j = 0; j < 4; ++j)                                    \
                    acc[j] = __builtin_amdgcn_mfma_f32_16x16x32_fp8_fp8(       \
                        A[ks], Breg[ks * 4 + j], acc[j], 0, 0, 0);             \
            int crow = rg * 16 + kg * 4;                                       \
            _Pragma("unroll")                                                  \
            for (int j = 0; j < 4; ++j)                                        \
                _Pragma("unroll")                                              \
                for (int r = 0; r < 4; ++r)                                    \
                    cb[(size_t)(t) * 8192 + (size_t)(crow + r) * 256 +         \
                       j * 16 + r16] = acc[j][r] * outscale;                   \
        }                                                                      \
    } while (0)

__global__ __launch_bounds__(256, 2) void gemm_kernel(
    const float* __restrict__ x, const ll* __restrict__ Bpack,
    const float* __restrict__ partials, const float* __restrict__ kamaxf,
    const float* __restrict__ input_scale, const float* __restrict__ kernel_scale,
    float* __restrict__ C) {
    __shared__ char lds[2][32 * 256];  // double-buffered fp8 tiles

    int tid = threadIdx.x;
    int w = tid >> 6;
    int lane = tid & 63;
    int kg = lane >> 4, r16 = lane & 15;
    unsigned sw = (unsigned)(r16 << 3);

    // Compiler-visible preamble (its loads are fully drained below so later
    // compiler-emitted waits can never drain our asm prefetches).
    ll Breg[32];  // [ks*4+j]
    #pragma unroll
    for (int i = 0; i < 32; ++i)
        Breg[i] = Bpack[(i >> 2) * 1024 + (w * 4 + (i & 3)) * 64 + lane];

    const f32x4* pp = (const f32x4*)partials;
    float m = 0.0f;
    #pragma unroll
    for (int i = 0; i < 8; ++i)
        m = amax4(pp[lane + i * 64], m);
    #pragma unroll
    for (int off = 32; off; off >>= 1)
        m = fmaxf(m, __shfl_xor(m, off, 64));
    float sf_x = scale_factor(m, input_scale[0]);
    float sf_k = scale_factor(kamaxf[0], kernel_scale[0]);
    float outscale = (1.0f / sf_x) * (1.0f / sf_k);

    asm volatile("s_waitcnt vmcnt(0) lgkmcnt(0)" ::: "memory");
    __builtin_amdgcn_sched_barrier(0);

    const float* xt = x + (size_t)blockIdx.x * 128 * 256;
    float* cb = C + (size_t)blockIdx.x * 128 * 256 + w * 64;

    f32x4 raw0[8], raw1[8], raw2[8];

    ISSUE(raw0, 0);
    ISSUE(raw1, 1);
    ISSUE(raw2, 2);

    // t0: outstanding 24 -> drain raw0 only.
    asm volatile("s_waitcnt vmcnt(16)" ::: "memory");
    __builtin_amdgcn_sched_barrier(0);
    TILE(raw0, 0, 0);

    // t1: issue raw3 into raw0's regs (freed by t0's quant).
    ISSUE(raw0, 3);
    asm volatile("s_waitcnt vmcnt(48)" ::: "memory");  // drains raw1
    __builtin_amdgcn_sched_barrier(0);
    TILE(raw1, 1, 1);

    // t2: drains raw2 (stores0 forced out too; raw3 stays in flight).
    asm volatile("s_waitcnt vmcnt(40)" ::: "memory");
    __builtin_amdgcn_sched_barrier(0);
    TILE(raw2, 0, 2);

    // t3: drains raw3; stores1 stay in flight.
    asm volatile("s_waitcnt vmcnt(32)" ::: "memory");
    __builtin_amdgcn_sched_barrier(0);
    TILE(raw0, 1, 3);
}

// ---------------------------------------------------------------------------
extern "C" void kernel_launch(void* const* d_in, const int* in_sizes, int n_in,
                              void* d_out, int out_size, void* d_ws, size_t ws_size,
                              hipStream_t stream) {
    const float* x = (const float*)d_in[0];             // [8,8192,256] f32
    const float* k = (const float*)d_in[1];             // [256,256] f32
    const float* input_scale = (const float*)d_in[2];   // [1]
    const float* kernel_scale = (const float*)d_in[3];  // [1]
    float* out = (float*)d_out;

    float* partials = (float*)d_ws;                     // [2048]
    float* kamaxf = partials + 2048;                    // [1]
    ll* pack = (ll*)((char*)d_ws + 16384);              // 64 KiB packed fp8 B

    int nx = in_sizes[0];                               // 16,777,216
    int M = nx / 256;                                   // 65,536 rows

    prep_kernel<<<NXB + KBLK, 256, 0, stream>>>(x, k, kernel_scale,
                                                partials, kamaxf, pack);
    gemm_kernel<<<M / 128, 256, 0, stream>>>(x, pack, partials, kamaxf,
                                             input_scale, kernel_scale, out);
}